// Round 1
// baseline (6066.145 us; speedup 1.0000x reference)
//
#include <hip/hip_runtime.h>
#include <math.h>
#include <stdint.h>

// Problem constants (Qwen3-MoE block)
constexpr int Bc = 2, Sc = 2048, Hc = 2048, Ec = 64, Kc = 8, Ic = 768;
constexpr int Tc  = Bc * Sc;   // 4096 tokens
constexpr int TKc = Tc * Kc;   // 32768 dispatched rows

// ---------------------------------------------------------------------------
// Router: logits = x @ gw^T, softmax-top8 (renormalized), count tokens/expert
// One block (4 waves) per token.
// ---------------------------------------------------------------------------
__global__ __launch_bounds__(256) void router_topk(
    const float* __restrict__ x, const float* __restrict__ gw,
    int* __restrict__ topk_idx, float* __restrict__ topk_w,
    int* __restrict__ counts)
{
    __shared__ float xs[Hc];
    __shared__ float lg[Ec];
    const int t   = blockIdx.x;
    const int tid = threadIdx.x;

    // stage token row into LDS (2048 floats, 2 float4 per thread)
    {
        const float4* src = (const float4*)(x + (size_t)t * Hc);
        float4* dst = (float4*)xs;
        dst[tid * 2]     = src[tid * 2];
        dst[tid * 2 + 1] = src[tid * 2 + 1];
    }
    __syncthreads();

    const int wave = tid >> 6, lane = tid & 63;
    // each wave computes 16 expert logits
    for (int j = 0; j < 16; ++j) {
        const int e = wave * 16 + j;
        const float* gr = gw + (size_t)e * Hc;
        float p = 0.f;
        for (int i = lane; i < Hc; i += 64) p += xs[i] * gr[i];
        for (int off = 32; off; off >>= 1) p += __shfl_down(p, off);
        if (lane == 0) lg[e] = p;
    }
    __syncthreads();

    // wave 0: top-8 by repeated wave-argmax (lower index wins ties, like top_k)
    if (tid < 64) {
        float v = lg[lane];
        int   id = lane;
        float sval[8]; int sid[8];
        for (int k = 0; k < 8; ++k) {
            float bv = v; int bi = id;
            for (int off = 32; off; off >>= 1) {
                float ov = __shfl_down(bv, off);
                int   oi = __shfl_down(bi, off);
                if (ov > bv || (ov == bv && oi < bi)) { bv = ov; bi = oi; }
            }
            bv = __shfl(bv, 0); bi = __shfl(bi, 0);
            sval[k] = bv; sid[k] = bi;
            if (id == bi) v = -INFINITY;
        }
        if (lane == 0) {
            // softmax denominator cancels under renormalization:
            // w_k = exp(l_k - l_max) / sum_topk exp(l_j - l_max)
            float m = sval[0], s = 0.f, w[8];
            for (int k = 0; k < 8; ++k) { w[k] = expf(sval[k] - m); s += w[k]; }
            const float inv = 1.f / s;
            for (int k = 0; k < 8; ++k) {
                topk_idx[t * 8 + k] = sid[k];
                topk_w[t * 8 + k]   = w[k] * inv;
                atomicAdd(&counts[sid[k]], 1);
            }
        }
    }
}

// ---------------------------------------------------------------------------
// Exclusive prefix sum over 64 expert counts (trivial single-thread scan)
// ---------------------------------------------------------------------------
__global__ void prefix_scan(const int* __restrict__ counts, int* __restrict__ offsets)
{
    if (threadIdx.x == 0 && blockIdx.x == 0) {
        int s = 0;
        for (int e = 0; e < Ec; ++e) { offsets[e] = s; s += counts[e]; }
        offsets[Ec] = s;   // == TKc
    }
}

// ---------------------------------------------------------------------------
// Scatter: expert-grouped row map.  rowtok[pos] = t*8+k  (pos grouped by expert)
// ---------------------------------------------------------------------------
__global__ __launch_bounds__(256) void scatter_rows(
    const int* __restrict__ topk_idx, const int* __restrict__ offsets,
    int* __restrict__ cursor, int* __restrict__ rowtok)
{
    const int idx = blockIdx.x * 256 + threadIdx.x;
    if (idx < TKc) {
        const int e   = topk_idx[idx];
        const int pos = offsets[e] + atomicAdd(&cursor[e], 1);
        rowtok[pos] = idx;
    }
}

// ---------------------------------------------------------------------------
// Grouped GEMM 1: act[pos, i] = silu(x@Wg) * (x@Wu), per expert.
// BM=BN=64, BK=16, 256 threads, 4x4 microtile per thread, gate+up fused.
// grid = (I/64, E, 64 row-tiles max) with early exit on empty tiles.
// ---------------------------------------------------------------------------
__global__ __launch_bounds__(256) void gemm_act(
    const float* __restrict__ x, const float* __restrict__ wg,
    const float* __restrict__ wu, const int* __restrict__ offsets,
    const int* __restrict__ rowtok, float* __restrict__ act)
{
    __shared__ float As[64][17];
    __shared__ float Bg[16][68];
    __shared__ float Bu[16][68];

    const int e    = blockIdx.y;
    const int base = offsets[e];
    const int M    = offsets[e + 1] - base;
    const int row0 = blockIdx.z * 64;
    if (row0 >= M) return;
    const int n0  = blockIdx.x * 64;
    const int tid = threadIdx.x;

    // A-load mapping: thread -> (row ar, float4 quad aq)
    const int ar = tid >> 2, aq = tid & 3;
    const bool avalid = (row0 + ar) < M;
    const int tok = avalid ? (rowtok[base + row0 + ar] >> 3) : 0;
    const float* arow = x + (size_t)tok * Hc + aq * 4;

    // B-load mapping: thread -> (k-row bk, float4 quad bq)
    const int bk = tid >> 4, bq = tid & 15;
    const float* wg_base = wg + (size_t)e * Hc * Ic + n0;
    const float* wu_base = wu + (size_t)e * Hc * Ic + n0;

    const int tr = tid >> 4, tc = tid & 15;
    float accg[4][4] = {}, accu[4][4] = {};

    for (int h0 = 0; h0 < Hc; h0 += 16) {
        float4 av = make_float4(0.f, 0.f, 0.f, 0.f);
        if (avalid) av = *(const float4*)(arow + h0);
        As[ar][aq * 4 + 0] = av.x; As[ar][aq * 4 + 1] = av.y;
        As[ar][aq * 4 + 2] = av.z; As[ar][aq * 4 + 3] = av.w;

        const float4 gv = *(const float4*)(wg_base + (size_t)(h0 + bk) * Ic + bq * 4);
        const float4 uv = *(const float4*)(wu_base + (size_t)(h0 + bk) * Ic + bq * 4);
        Bg[bk][bq * 4 + 0] = gv.x; Bg[bk][bq * 4 + 1] = gv.y;
        Bg[bk][bq * 4 + 2] = gv.z; Bg[bk][bq * 4 + 3] = gv.w;
        Bu[bk][bq * 4 + 0] = uv.x; Bu[bk][bq * 4 + 1] = uv.y;
        Bu[bk][bq * 4 + 2] = uv.z; Bu[bk][bq * 4 + 3] = uv.w;
        __syncthreads();

        #pragma unroll
        for (int kk = 0; kk < 16; ++kk) {
            float a[4], bg[4], bu[4];
            #pragma unroll
            for (int i2 = 0; i2 < 4; ++i2) a[i2] = As[tr * 4 + i2][kk];
            #pragma unroll
            for (int j = 0; j < 4; ++j) { bg[j] = Bg[kk][tc * 4 + j]; bu[j] = Bu[kk][tc * 4 + j]; }
            #pragma unroll
            for (int i2 = 0; i2 < 4; ++i2)
                #pragma unroll
                for (int j = 0; j < 4; ++j) {
                    accg[i2][j] += a[i2] * bg[j];
                    accu[i2][j] += a[i2] * bu[j];
                }
        }
        __syncthreads();
    }

    #pragma unroll
    for (int i2 = 0; i2 < 4; ++i2) {
        const int r = tr * 4 + i2;
        if (row0 + r < M) {
            float* orow = act + (size_t)(base + row0 + r) * Ic + n0 + tc * 4;
            #pragma unroll
            for (int j = 0; j < 4; ++j) {
                const float g = accg[i2][j], u = accu[i2][j];
                const float s = g / (1.f + expf(-g));   // silu
                orow[j] = s * u;
            }
        }
    }
}

// ---------------------------------------------------------------------------
// Grouped GEMM 2: out[t] += w_{t,k} * (act @ Wd), per expert. Atomic combine.
// grid = (H/64, E, 64 row-tiles max)
// ---------------------------------------------------------------------------
__global__ __launch_bounds__(256) void gemm_down(
    const float* __restrict__ act, const float* __restrict__ wd,
    const int* __restrict__ offsets, const int* __restrict__ rowtok,
    const float* __restrict__ topk_w, float* __restrict__ out)
{
    __shared__ float As[64][17];
    __shared__ float Bs[16][68];

    const int e    = blockIdx.y;
    const int base = offsets[e];
    const int M    = offsets[e + 1] - base;
    const int row0 = blockIdx.z * 64;
    if (row0 >= M) return;
    const int n0  = blockIdx.x * 64;
    const int tid = threadIdx.x;

    const int ar = tid >> 2, aq = tid & 3;
    const bool avalid = (row0 + ar) < M;
    const float* arow = act + (size_t)(base + row0 + ar) * Ic + aq * 4;

    const int bk = tid >> 4, bq = tid & 15;
    const float* wd_base = wd + (size_t)e * Ic * Hc + n0;

    const int tr = tid >> 4, tc = tid & 15;
    float acc[4][4] = {};

    for (int i0 = 0; i0 < Ic; i0 += 16) {
        float4 av = make_float4(0.f, 0.f, 0.f, 0.f);
        if (avalid) av = *(const float4*)(arow + i0);
        As[ar][aq * 4 + 0] = av.x; As[ar][aq * 4 + 1] = av.y;
        As[ar][aq * 4 + 2] = av.z; As[ar][aq * 4 + 3] = av.w;

        const float4 bv = *(const float4*)(wd_base + (size_t)(i0 + bk) * Hc + bq * 4);
        Bs[bk][bq * 4 + 0] = bv.x; Bs[bk][bq * 4 + 1] = bv.y;
        Bs[bk][bq * 4 + 2] = bv.z; Bs[bk][bq * 4 + 3] = bv.w;
        __syncthreads();

        #pragma unroll
        for (int kk = 0; kk < 16; ++kk) {
            float a[4], b[4];
            #pragma unroll
            for (int i2 = 0; i2 < 4; ++i2) a[i2] = As[tr * 4 + i2][kk];
            #pragma unroll
            for (int j = 0; j < 4; ++j) b[j] = Bs[kk][tc * 4 + j];
            #pragma unroll
            for (int i2 = 0; i2 < 4; ++i2)
                #pragma unroll
                for (int j = 0; j < 4; ++j) acc[i2][j] += a[i2] * b[j];
        }
        __syncthreads();
    }

    #pragma unroll
    for (int i2 = 0; i2 < 4; ++i2) {
        const int r = tr * 4 + i2;
        if (row0 + r < M) {
            const int idx = rowtok[base + row0 + r];
            const int t   = idx >> 3;
            const float w = topk_w[idx];
            float* orow = out + (size_t)t * Hc + n0 + tc * 4;
            #pragma unroll
            for (int j = 0; j < 4; ++j) atomicAdd(&orow[j], w * acc[i2][j]);
        }
    }
}

// ---------------------------------------------------------------------------
extern "C" void kernel_launch(void* const* d_in, const int* in_sizes, int n_in,
                              void* d_out, int out_size, void* d_ws, size_t ws_size,
                              hipStream_t stream)
{
    const float* x  = (const float*)d_in[0];   // [B,S,H]
    const float* gw = (const float*)d_in[1];   // [E,H]
    const float* wg = (const float*)d_in[2];   // [E,H,I]
    const float* wu = (const float*)d_in[3];   // [E,H,I]
    const float* wd = (const float*)d_in[4];   // [E,I,H]
    float* out = (float*)d_out;                // [B,S,H]

    // workspace layout (4B words)
    int*   topk_idx = (int*)d_ws;                       // TKc
    float* topk_w   = (float*)(topk_idx + TKc);         // TKc
    int*   counts   = (int*)(topk_w + TKc);             // Ec
    int*   offsets  = counts + Ec;                      // Ec+1
    int*   cursor   = offsets + Ec + 1;                 // Ec
    int*   rowtok   = cursor + Ec;                      // TKc
    float* act      = (float*)((((uintptr_t)(rowtok + TKc)) + 255) & ~(uintptr_t)255); // TKc*Ic

    // zero the control block (counts/offsets/cursor) and the output
    hipMemsetAsync(counts, 0, (size_t)(3 * Ec + 1) * sizeof(int), stream);
    hipMemsetAsync(out, 0, (size_t)out_size * sizeof(float), stream);

    router_topk<<<Tc, 256, 0, stream>>>(x, gw, topk_idx, topk_w, counts);
    prefix_scan<<<1, 64, 0, stream>>>(counts, offsets);
    scatter_rows<<<TKc / 256, 256, 0, stream>>>(topk_idx, offsets, cursor, rowtok);
    gemm_act<<<dim3(Ic / 64, Ec, 64), 256, 0, stream>>>(x, wg, wu, offsets, rowtok, act);
    gemm_down<<<dim3(Hc / 64, Ec, 64), 256, 0, stream>>>(act, wd, offsets, rowtok, topk_w, out);
}